// Round 2
// baseline (282.262 us; speedup 1.0000x reference)
//
#include <hip/hip_runtime.h>

#define HEADS 4
#define OUTC 64
#define INC 128
#define HC 256   // HEADS*OUTC
#define NEG 0.2f

typedef __attribute__((ext_vector_type(8))) short bf16x8;
typedef __attribute__((ext_vector_type(4))) float f32x4;

static __device__ __forceinline__ float bf2f(unsigned short u){
  unsigned int x = ((unsigned int)u) << 16;
  return __uint_as_float(x);
}
static __device__ __forceinline__ float bflo(unsigned int u){
  return __uint_as_float(u << 16);
}
static __device__ __forceinline__ float bfhi(unsigned int u){
  return __uint_as_float(u & 0xffff0000u);
}
static __device__ __forceinline__ unsigned short f2bf(float f){
  unsigned int x = __float_as_uint(f);
  unsigned int lsb = (x >> 16) & 1u;
  x += 0x7fffu + lsb;           // RNE
  return (unsigned short)(x >> 16);
}
static __device__ __forceinline__ void split8(float4 a, float4 b, bf16x8& hi, bf16x8& lo){
  float v[8] = {a.x, a.y, a.z, a.w, b.x, b.y, b.z, b.w};
  #pragma unroll
  for (int i = 0; i < 8; ++i){
    unsigned short h = f2bf(v[i]);
    hi[i] = (short)h;
    lo[i] = (short)f2bf(v[i] - bf2f(h));
  }
}

// ---- edge canonicalize (per-wave int64/int32 detection) + degree histogram ----
__global__ void k_conv_e_hist(const int* __restrict__ ei,
                              int* __restrict__ srcc, int* __restrict__ dstc,
                              int* __restrict__ pos, int* __restrict__ deg, int E){
  int e = blockIdx.x * 256 + threadIdx.x;
  bool valid = (e < E);
  int ee = valid ? e : 0;
  int hiw = ei[2 * ee + 1];
  bool hz = valid ? (hiw == 0) : true;
  unsigned long long mask = __ballot(hz);
  bool i64 = (mask == ~0ULL);
  int s, d;
  if (i64){ s = ei[2 * ee]; d = ei[2 * (size_t)E + 2 * ee]; }
  else    { s = ei[ee];     d = ei[(size_t)E + ee]; }
  if (valid){
    srcc[e] = s; dstc[e] = d;
    pos[e] = atomicAdd(&deg[d], 1);
  }
}

// ---- split + transpose W into bf16 hi/lo ----
__global__ void k_split_w(const float* __restrict__ W, unsigned short* __restrict__ Wthi,
                          unsigned short* __restrict__ Wtlo){
  int t = blockIdx.x * 256 + threadIdx.x;        // 0..32767
  int k = t >> 8, n = t & 255;
  float v = W[t];
  unsigned short hi = f2bf(v);
  Wthi[n * INC + k] = hi;
  Wtlo[n * INC + k] = f2bf(v - bf2f(hi));
}

// ---- fused GEMM + attention logits ----
// Wave = one 16-row tile x all 256 cols (16 MFMA col-tiles).
// Each X row is loaded+split exactly ONCE (was 4x redundant per block);
// B tiles stream from L2-hot W (128 KB total). Register pressure ~130 -> 4 waves/SIMD.
__global__ __launch_bounds__(256) void k_gemm_fused(const float* __restrict__ X,
    const unsigned short* __restrict__ Wthi, const unsigned short* __restrict__ Wtlo,
    const float* __restrict__ att_src, const float* __restrict__ att_dst,
    unsigned short* __restrict__ XPh, float* __restrict__ a_src, float* __restrict__ a_dst,
    int N){
  int w = threadIdx.x >> 6, lane = threadIdx.x & 63;
  int quad = lane >> 4, l15 = lane & 15;
  int rt = blockIdx.x * 4 + w;                   // row-tile index, waves independent
  int row0 = rt * 16;
  if (row0 >= N) return;                         // N%16==0 -> surviving tiles fully valid
  int row = row0 + l15;

  f32x4 acc[16];
  #pragma unroll
  for (int t = 0; t < 16; ++t) acc[t] = (f32x4){0.f, 0.f, 0.f, 0.f};

  #pragma unroll
  for (int kk = 0; kk < 4; ++kk){
    const float* xr = X + (size_t)row * INC + kk * 32 + quad * 8;
    float4 va = *(const float4*)xr;
    float4 vb = *(const float4*)(xr + 4);
    bf16x8 ah, al;
    split8(va, vb, ah, al);                      // one split per kk (was 4)
    #pragma unroll
    for (int tg = 0; tg < 4; ++tg){
      bf16x8 bh[4], bl[4];
      #pragma unroll
      for (int q = 0; q < 4; ++q){
        size_t bo = (size_t)((tg * 4 + q) * 16 + l15) * INC + kk * 32 + quad * 8;
        bh[q] = *(const bf16x8*)(Wthi + bo);
        bl[q] = *(const bf16x8*)(Wtlo + bo);
      }
      #pragma unroll
      for (int q = 0; q < 4; ++q){
        int t = tg * 4 + q;
        acc[t] = __builtin_amdgcn_mfma_f32_16x16x32_bf16(ah, bh[q], acc[t], 0, 0, 0);
        acc[t] = __builtin_amdgcn_mfma_f32_16x16x32_bf16(ah, bl[q], acc[t], 0, 0, 0);
        acc[t] = __builtin_amdgcn_mfma_f32_16x16x32_bf16(al, bh[q], acc[t], 0, 0, 0);
      }
    }
  }

  // store XPh (bf16). C/D layout: col=l15, row=quad*4+r
  #pragma unroll
  for (int t = 0; t < 16; ++t){
    #pragma unroll
    for (int r = 0; r < 4; ++r){
      XPh[(size_t)(row0 + quad * 4 + r) * HC + t * 16 + l15] = f2bf(acc[t][r]);
    }
  }

  // logits: per head hh, a_src[n][hh] = sum over its 4 col-tiles + 16 lanes
  float as_[16], ad_[16];
  #pragma unroll
  for (int t = 0; t < 16; ++t){
    as_[t] = att_src[t * 16 + l15];
    ad_[t] = att_dst[t * 16 + l15];
  }
  #pragma unroll
  for (int r = 0; r < 4; ++r){
    float psel = 0.f, pdel = 0.f;
    #pragma unroll
    for (int hh = 0; hh < 4; ++hh){
      float sv = 0.f, dv = 0.f;
      #pragma unroll
      for (int q = 0; q < 4; ++q){
        int t = hh * 4 + q;
        sv += acc[t][r] * as_[t];
        dv += acc[t][r] * ad_[t];
      }
      #pragma unroll
      for (int msk = 1; msk < 16; msk <<= 1){
        sv += __shfl_xor(sv, msk, 64);
        dv += __shfl_xor(dv, msk, 64);
      }
      if (l15 == hh){ psel = sv; pdel = dv; }
    }
    int nrow = row0 + quad * 4 + r;
    if (l15 < 4){
      a_src[nrow * HEADS + l15] = psel;
      a_dst[nrow * HEADS + l15] = pdel;
    }
  }
}

// ---- exclusive scan over deg, phase 1 ----
__global__ __launch_bounds__(256) void k_scan1(const int* __restrict__ deg,
                                               int* __restrict__ out,
                                               int* __restrict__ bsum, int N){
  __shared__ int tsum[256];
  int t = threadIdx.x;
  int base = blockIdx.x * 1024 + t * 4;
  int v[4]; int s = 0;
  #pragma unroll
  for (int k = 0; k < 4; ++k){ int i = base + k; v[k] = (i < N) ? deg[i] : 0; s += v[k]; }
  tsum[t] = s;
  __syncthreads();
  for (int off = 1; off < 256; off <<= 1){
    int x = (t >= off) ? tsum[t - off] : 0;
    __syncthreads();
    tsum[t] += x;
    __syncthreads();
  }
  int excl = tsum[t] - s;
  if (t == 255) bsum[blockIdx.x] = tsum[255];
  int run = excl;
  #pragma unroll
  for (int k = 0; k < 4; ++k){ int i = base + k; if (i < N) out[i] = run; run += v[k]; }
}

// ---- phase 2+3 merged ----
__global__ __launch_bounds__(256) void k_scan23(int* __restrict__ rowstart,
                                                const int* __restrict__ bsum,
                                                int N, int E){
  int lane = threadIdx.x & 63;
  int partial = 0;
  for (int i = lane; i < blockIdx.x; i += 64) partial += bsum[i];
  #pragma unroll
  for (int msk = 32; msk; msk >>= 1) partial += __shfl_xor(partial, msk, 64);
  int base = blockIdx.x * 1024 + threadIdx.x * 4;
  #pragma unroll
  for (int k = 0; k < 4; ++k){ int i = base + k; if (i < N) rowstart[i] += partial; }
  if (blockIdx.x == 0 && threadIdx.x == 0) rowstart[N] = E;
}

// ---- scatter (atomic-free) ----
__global__ void k_scatter(const int* __restrict__ srcc, const int* __restrict__ dstc,
                          const int* __restrict__ pos, const int* __restrict__ rowstart,
                          int* __restrict__ csr, int E){
  int e = blockIdx.x * 256 + threadIdx.x;
  if (e < E){
    int d = dstc[e];
    csr[rowstart[d] + pos[e]] = srcc[e];
  }
}

// ---- fused softmax-coef + gather: wave = node (all 4 heads) ----
// Each lane carries 16 B (8 cols); 32 lanes = full 512-B row,
// the two wave halves process TWO edges per load instruction (half the VMEM
// instruction count at identical bytes). Halves combined by one shfl_xor(32).
__global__ __launch_bounds__(256) void k_fused(const unsigned short* __restrict__ XPh,
    const float* __restrict__ a_src, const float* __restrict__ a_dst,
    const int* __restrict__ rowstart, const int* __restrict__ csr,
    const float* __restrict__ bias, float* __restrict__ out, int N){
  __shared__ float sh[4][64][4];               // [wave][slot][head]
  int w = threadIdx.x >> 6, lane = threadIdx.x & 63;
  int n = blockIdx.x * 4 + w;
  bool alive = (n < N);
  if (!alive) n = 0;
  int r0 = rowstart[n], r1 = rowstart[n + 1];
  int deg = r1 - r0;
  int total = deg + 1;
  float4 ad4 = *(const float4*)&a_dst[n * HEADS];
  bool fast = (total <= 64);
  int jv = n;
  float mH0 = 0.f, mH1 = 0.f, mH2 = 0.f, mH3 = 0.f;   // slow-path per-head max
  float iH0 = 0.f, iH1 = 0.f, iH2 = 0.f, iH3 = 0.f;   // slow-path per-head 1/sum

  if (fast){
    if (lane < deg) jv = csr[r0 + lane];
    float l0 = -1e30f, l1 = -1e30f, l2 = -1e30f, l3 = -1e30f;
    if (lane < total){
      float4 a4 = *(const float4*)&a_src[jv * HEADS];
      l0 = a4.x + ad4.x; l0 = (l0 > 0.f) ? l0 : NEG * l0;
      l1 = a4.y + ad4.y; l1 = (l1 > 0.f) ? l1 : NEG * l1;
      l2 = a4.z + ad4.z; l2 = (l2 > 0.f) ? l2 : NEG * l2;
      l3 = a4.w + ad4.w; l3 = (l3 > 0.f) ? l3 : NEG * l3;
    }
    float p0 = __expf(l0), p1 = __expf(l1), p2 = __expf(l2), p3 = __expf(l3);
    float s0 = p0, s1 = p1, s2 = p2, s3 = p3;
    #pragma unroll
    for (int msk = 32; msk; msk >>= 1){
      s0 += __shfl_xor(s0, msk, 64);
      s1 += __shfl_xor(s1, msk, 64);
      s2 += __shfl_xor(s2, msk, 64);
      s3 += __shfl_xor(s3, msk, 64);
    }
    if (lane < total){
      float4 cv; cv.x = p0 / s0; cv.y = p1 / s1; cv.z = p2 / s2; cv.w = p3 / s3;
      *(float4*)&sh[w][lane][0] = cv;
    }
  } else {
    float m[4] = {-1e30f, -1e30f, -1e30f, -1e30f};
    float s[4] = {0.f, 0.f, 0.f, 0.f};
    float adArr[4] = {ad4.x, ad4.y, ad4.z, ad4.w};
    for (int e = lane; e < total; e += 64){
      int j = (e < deg) ? csr[r0 + e] : n;
      float4 a4 = *(const float4*)&a_src[j * HEADS];
      float aa[4] = {a4.x, a4.y, a4.z, a4.w};
      #pragma unroll
      for (int hh = 0; hh < 4; ++hh){
        float l = aa[hh] + adArr[hh];
        l = (l > 0.f) ? l : NEG * l;
        if (l > m[hh]){ s[hh] = s[hh] * __expf(m[hh] - l) + 1.f; m[hh] = l; }
        else            s[hh] += __expf(l - m[hh]);
      }
    }
    #pragma unroll
    for (int hh = 0; hh < 4; ++hh){
      float mm = m[hh], ss = s[hh];
      #pragma unroll
      for (int msk = 32; msk; msk >>= 1){
        float m2 = __shfl_xor(mm, msk, 64);
        float s2 = __shfl_xor(ss, msk, 64);
        float M = fmaxf(mm, m2);
        float ns = 0.f;
        if (mm > -1e29f) ns += ss * __expf(mm - M);
        if (m2 > -1e29f) ns += s2 * __expf(m2 - M);
        mm = M; ss = ns;
      }
      m[hh] = mm; s[hh] = ss;
    }
    mH0 = m[0]; mH1 = m[1]; mH2 = m[2]; mH3 = m[3];
    iH0 = 1.f / s[0]; iH1 = 1.f / s[1]; iH2 = 1.f / s[2]; iH3 = 1.f / s[3];
  }

  __syncthreads();

  int half = lane >> 5, l32 = lane & 31;
  int hh = l32 >> 3;                           // head owning this lane's 8 cols
  const unsigned short* xb = XPh + l32 * 8;    // 16 B per lane within a row
  float a0 = 0.f, a1 = 0.f, a2 = 0.f, a3 = 0.f, a4_ = 0.f, a5 = 0.f, a6 = 0.f, a7 = 0.f;

  if (fast){
    for (int e = 0; e < total; e += 16){       // masked batch: always 8 loads in flight
      int jj[8]; float cf[8];
      #pragma unroll
      for (int q = 0; q < 8; ++q){
        int s0i = e + 2 * q, s1i = s0i + 1;
        int c0 = (s0i < total) ? s0i : (total - 1);
        int c1 = (s1i < total) ? s1i : (total - 1);
        int j0 = __builtin_amdgcn_readlane(jv, c0);
        int j1 = __builtin_amdgcn_readlane(jv, c1);
        jj[q] = half ? j1 : j0;
        int sl = s0i + half;
        int slc = (sl < total) ? sl : 0;
        cf[q] = (sl < total) ? sh[w][slc][hh] : 0.f;
      }
      uint4 xv[8];
      #pragma unroll
      for (int q = 0; q < 8; ++q) xv[q] = *(const uint4*)(xb + (size_t)jj[q] * HC);
      #pragma unroll
      for (int q = 0; q < 8; ++q){
        float c = cf[q];
        a0  += c * bflo(xv[q].x); a1 += c * bfhi(xv[q].x);
        a2  += c * bflo(xv[q].y); a3 += c * bfhi(xv[q].y);
        a4_ += c * bflo(xv[q].z); a5 += c * bfhi(xv[q].z);
        a6  += c * bflo(xv[q].w); a7 += c * bfhi(xv[q].w);
      }
    }
  } else {
    float adh = (hh == 0) ? ad4.x : (hh == 1) ? ad4.y : (hh == 2) ? ad4.z : ad4.w;
    float mh  = (hh == 0) ? mH0 : (hh == 1) ? mH1 : (hh == 2) ? mH2 : mH3;
    float ih  = (hh == 0) ? iH0 : (hh == 1) ? iH1 : (hh == 2) ? iH2 : iH3;
    for (int e = 0; e < total; e += 2){
      int eh = e + half;
      bool has = (eh < total);
      int ec = has ? eh : (total - 1);
      int j = (ec < deg) ? csr[r0 + ec] : n;
      float4 s4 = *(const float4*)&a_src[j * HEADS];
      float ahv = (hh == 0) ? s4.x : (hh == 1) ? s4.y : (hh == 2) ? s4.z : s4.w;
      float l = ahv + adh;
      l = (l > 0.f) ? l : NEG * l;
      float c = has ? (__expf(l - mh) * ih) : 0.f;
      uint4 xv = *(const uint4*)(xb + (size_t)j * HC);
      a0  += c * bflo(xv.x); a1 += c * bfhi(xv.x);
      a2  += c * bflo(xv.y); a3 += c * bfhi(xv.y);
      a4_ += c * bflo(xv.z); a5 += c * bfhi(xv.z);
      a6  += c * bflo(xv.w); a7 += c * bfhi(xv.w);
    }
  }

  // combine the two halves (even edges in lanes 0-31, odd edges in lanes 32-63)
  a0  += __shfl_xor(a0, 32, 64);  a1 += __shfl_xor(a1, 32, 64);
  a2  += __shfl_xor(a2, 32, 64);  a3 += __shfl_xor(a3, 32, 64);
  a4_ += __shfl_xor(a4_, 32, 64); a5 += __shfl_xor(a5, 32, 64);
  a6  += __shfl_xor(a6, 32, 64);  a7 += __shfl_xor(a7, 32, 64);

  if (alive){
    float4 b4 = *(const float4*)&bias[l32 * 8 + half * 4];
    f32x4 r;
    r[0] = (half ? a4_ : a0) + b4.x;
    r[1] = (half ? a5  : a1) + b4.y;
    r[2] = (half ? a6  : a2) + b4.z;
    r[3] = (half ? a7  : a3) + b4.w;
    // write-once 50 MB output: non-temporal so it doesn't evict XPh gather lines
    __builtin_nontemporal_store(r, (f32x4*)&out[(size_t)n * HC + l32 * 8 + half * 4]);
  }
}

extern "C" void kernel_launch(void* const* d_in, const int* in_sizes, int n_in,
                              void* d_out, int out_size, void* d_ws, size_t ws_size,
                              hipStream_t stream){
  const float* x       = (const float*)d_in[0];
  const float* W       = (const float*)d_in[1];
  const float* att_src = (const float*)d_in[2];
  const float* att_dst = (const float*)d_in[3];
  const float* bias    = (const float*)d_in[4];
  const int*   ei      = (const int*)d_in[5];
  int N = in_sizes[0] / INC;     // 50000
  int E = in_sizes[5] / 2;       // 800000

  char* p = (char*)d_ws;
  auto alloc = [&](size_t bytes)->char*{
    char* r = p; p += (bytes + 255) & ~(size_t)255; return r;
  };
  unsigned short* Wthi = (unsigned short*)alloc((size_t)INC * HC * 2);
  unsigned short* Wtlo = (unsigned short*)alloc((size_t)INC * HC * 2);
  unsigned short* XPh  = (unsigned short*)alloc((size_t)N * HC * 2);
  float* aSrc          = (float*)alloc((size_t)N * HEADS * 4);
  float* aDst          = (float*)alloc((size_t)N * HEADS * 4);
  int* deg             = (int*)alloc((size_t)N * 4);
  int* rowstart        = (int*)alloc(((size_t)N + 1) * 4);
  int* srcc            = (int*)alloc((size_t)E * 4);
  int* dstc            = (int*)alloc((size_t)E * 4);
  int* pos             = (int*)alloc((size_t)E * 4);
  int* csr             = (int*)alloc((size_t)E * 4);
  int* bsum            = (int*)alloc(256 * 4);

  hipMemsetAsync(deg, 0, (size_t)N * 4, stream);
  k_conv_e_hist<<<(E + 255) / 256, 256, 0, stream>>>(ei, srcc, dstc, pos, deg, E);

  k_split_w<<<(INC * HC) / 256, 256, 0, stream>>>(W, Wthi, Wtlo);
  k_gemm_fused<<<(N + 63) / 64, 256, 0, stream>>>(x, Wthi, Wtlo, att_src, att_dst,
                                                  XPh, aSrc, aDst, N);

  int nb = (N + 1023) / 1024;
  k_scan1<<<nb, 256, 0, stream>>>(deg, rowstart, bsum, N);
  k_scan23<<<nb, 256, 0, stream>>>(rowstart, bsum, N, E);
  k_scatter<<<(E + 255) / 256, 256, 0, stream>>>(srcc, dstc, pos, rowstart, csr, E);

  k_fused<<<(N + 3) / 4, 256, 0, stream>>>(XPh, aSrc, aDst, rowstart, csr, bias,
                                           (float*)d_out, N);
}